// Round 2
// baseline (286.041 us; speedup 1.0000x reference)
//
#include <hip/hip_runtime.h>
#include <hip/hip_bf16.h>
#include <math.h>

// Problem constants
#define B_   2
#define T_   2048
#define D_   2048
#define NH_  16
#define NKV_ 4
#define HD_  128
#define MROWS (B_*T_)          // 4096
#define NQKV  (NH_*HD_ + 2*NKV_*HD_)  // 3072

typedef __bf16 bf16_t;
typedef __bf16 bf16x8 __attribute__((ext_vector_type(8)));
typedef __bf16 bf16x4 __attribute__((ext_vector_type(4)));
typedef float  floatx4 __attribute__((ext_vector_type(4)));

// ---------------------------------------------------------------------------
// async global->LDS, 16B per lane. LDS dest must be wave-uniform base + lane*16.
__device__ __forceinline__ void async_copy16(const bf16_t* gsrc, bf16_t* ldst) {
  __builtin_amdgcn_global_load_lds(
      (const __attribute__((address_space(1))) unsigned int*)gsrc,
      (__attribute__((address_space(3))) unsigned int*)ldst, 16, 0, 0);
}

// ---------------------------------------------------------------------------
// Fused prep: z=0..3 -> transpose+cast weight z; z=4 -> elementwise cast of x.
// grid (64, 64, 5), block (32,8)
__global__ void prep_fused(const float* __restrict__ s0, const float* __restrict__ s1,
                           const float* __restrict__ s2, const float* __restrict__ s3,
                           const float* __restrict__ sx,
                           bf16_t* __restrict__ d0, bf16_t* __restrict__ d1,
                           bf16_t* __restrict__ d2, bf16_t* __restrict__ d3,
                           bf16_t* __restrict__ dx) {
  const int z = blockIdx.z;
  const int tx = threadIdx.x, ty = threadIdx.y;
  if (z == 4) {
    int i = ((blockIdx.y * 64 + blockIdx.x) * 256 + ty * 32 + tx) * 8;
    float4 a = *(const float4*)(sx + i);
    float4 b = *(const float4*)(sx + i + 4);
    bf16x8 v;
    v[0]=(bf16_t)a.x; v[1]=(bf16_t)a.y; v[2]=(bf16_t)a.z; v[3]=(bf16_t)a.w;
    v[4]=(bf16_t)b.x; v[5]=(bf16_t)b.y; v[6]=(bf16_t)b.z; v[7]=(bf16_t)b.w;
    *(bf16x8*)(dx + i) = v;
    return;
  }
  const int N = (z == 1 || z == 2) ? 512 : 2048;
  const int n0 = blockIdx.x * 32;
  if (n0 >= N) return;
  const float* src = (z == 0) ? s0 : (z == 1) ? s1 : (z == 2) ? s2 : s3;
  bf16_t*      dst = (z == 0) ? d0 : (z == 1) ? d1 : (z == 2) ? d2 : d3;
  const int K = 2048;
  __shared__ float tile[32][33];
  int k0 = blockIdx.y * 32;
#pragma unroll
  for (int r = 0; r < 4; r++)
    tile[ty + r*8][tx] = src[(size_t)(k0 + ty + r*8) * N + n0 + tx];
  __syncthreads();
#pragma unroll
  for (int r = 0; r < 4; r++)
    dst[(size_t)(n0 + ty + r*8) * K + k0 + tx] = (bf16_t)tile[tx][ty + r*8];
}

// ---------------------------------------------------------------------------
// C(M,N) = A(M,K) * Bt(N,K)^T   all bf16 in, OUT_T out.
// 128x128 tile, BK=64, 4 waves (2x2 of 64x64), 16x16x32 MFMA.
template <typename OUT_T>
__global__ __launch_bounds__(256, 3)
void gemm_bt(const bf16_t* __restrict__ A, const bf16_t* __restrict__ Bt,
             OUT_T* __restrict__ C, int M, int N, int K) {
  __shared__ __align__(16) bf16_t As[128 * 64];
  __shared__ __align__(16) bf16_t Bs[128 * 64];
  const int tid  = threadIdx.x;
  const int wave = tid >> 6, lane = tid & 63;
  const int quad = lane >> 4, l16 = lane & 15;
  const int nBlocksM = M >> 7;
  const int bm = blockIdx.x % nBlocksM, bn = blockIdx.x / nBlocksM;
  const int m0 = bm * 128, n0 = bn * 128;
  const int wm = (wave >> 1) * 64, wn = (wave & 1) * 64;

  floatx4 acc[4][4];
#pragma unroll
  for (int i = 0; i < 4; i++)
#pragma unroll
    for (int j = 0; j < 4; j++) acc[i][j] = floatx4{0.f, 0.f, 0.f, 0.f};

  for (int k0 = 0; k0 < K; k0 += 64) {
    __syncthreads();
#pragma unroll
    for (int i = 0; i < 4; i++) {
      int e = i * 256 + tid;
      int row = e >> 3, grp = e & 7;
      int gg = grp ^ (row & 7);
      async_copy16(A + (size_t)(m0 + row) * K + k0 + gg * 8, As + e * 8);
    }
#pragma unroll
    for (int i = 0; i < 4; i++) {
      int e = i * 256 + tid;
      int row = e >> 3, grp = e & 7;
      int gg = grp ^ (row & 7);
      async_copy16(Bt + (size_t)(n0 + row) * K + k0 + gg * 8, Bs + e * 8);
    }
    __syncthreads();
#pragma unroll
    for (int ks = 0; ks < 2; ks++) {
      bf16x8 af[4], bfr[4];
      int grp = ks * 4 + quad;
#pragma unroll
      for (int mi = 0; mi < 4; mi++) {
        int row = wm + mi * 16 + l16;
        af[mi] = *(const bf16x8*)(As + row * 64 + ((grp ^ (row & 7)) << 3));
      }
#pragma unroll
      for (int ni = 0; ni < 4; ni++) {
        int row = wn + ni * 16 + l16;
        bfr[ni] = *(const bf16x8*)(Bs + row * 64 + ((grp ^ (row & 7)) << 3));
      }
#pragma unroll
      for (int mi = 0; mi < 4; mi++)
#pragma unroll
        for (int ni = 0; ni < 4; ni++)
          acc[mi][ni] = __builtin_amdgcn_mfma_f32_16x16x32_bf16(af[mi], bfr[ni], acc[mi][ni], 0, 0, 0);
    }
  }
#pragma unroll
  for (int mi = 0; mi < 4; mi++) {
#pragma unroll
    for (int r = 0; r < 4; r++) {
      int row = m0 + wm + mi * 16 + quad * 4 + r;
      size_t base = (size_t)row * N + n0 + wn;
#pragma unroll
      for (int ni = 0; ni < 4; ni++)
        C[base + ni * 16 + l16] = (OUT_T)acc[mi][ni][r];
    }
  }
}

// ---------------------------------------------------------------------------
// Fused K-RoPE + V-transpose (one dispatch; branch is block-uniform).
// blocks [0,4096): rope_k — one thread per (row,kvh,j<64), qkv -> Kb roped.
// blocks [4096,6144): v_transpose — qkv V-slice (b,t,kv,d) -> Vt (B,NKV,HD,T).
#define ROPE_BLOCKS ((MROWS * NKV_ * 64) / 256)   // 4096
__global__ void kv_prep(const bf16_t* __restrict__ qkv, bf16_t* __restrict__ Kb,
                        bf16_t* __restrict__ Vt) {
  if (blockIdx.x < ROPE_BLOCKS) {
    int g = blockIdx.x * 256 + threadIdx.x;
    int j = g & 63;
    int rest = g >> 6;
    int kvh = rest & 3;
    int row = rest >> 2;                // b*T + t
    int t = row & (T_ - 1);
    int b = row >> 11;                  // T_ = 2048
    const bf16_t* src = qkv + (size_t)row * NQKV + NH_ * HD_ + kvh * HD_;
    float ang = (float)t * __expf(-0.14391156816f * (float)j);
    float sn, cs;
    __sincosf(ang, &sn, &cs);
    float x0 = (float)src[j];
    float x1 = (float)src[j + 64];
    bf16_t* dst = Kb + ((size_t)(b * NKV_ + kvh) * T_ + t) * HD_;
    dst[j]      = (bf16_t)(x0 * cs - x1 * sn);
    dst[j + 64] = (bf16_t)(x1 * cs + x0 * sn);
    return;
  }
  __shared__ float tile[32][33];
  int bb = blockIdx.x - ROPE_BLOCKS;          // [0, 2048)
  int bx = bb & 63, by = (bb >> 6) & 3, bz = bb >> 8;
  int t0 = bx * 32, d0 = by * 32;
  int b = bz / NKV_, kvh = bz % NKV_;
  int tx = threadIdx.x & 31, ty = threadIdx.x >> 5;
#pragma unroll
  for (int r = 0; r < 4; r++) {
    int t = t0 + ty + r * 8;
    tile[ty + r*8][tx] =
        (float)qkv[(size_t)(b * T_ + t) * NQKV + (NH_ + NKV_) * HD_ + kvh * HD_ + d0 + tx];
  }
  __syncthreads();
#pragma unroll
  for (int r = 0; r < 4; r++) {
    int d = d0 + ty + r * 8;
    Vt[((size_t)(b * NKV_ + kvh) * HD_ + d) * T_ + t0 + tx] = (bf16_t)tile[tx][ty + r*8];
  }
}

// ---------------------------------------------------------------------------
// Flash attention v5: S^T formulation + in-register Q-RoPE + REGISTER-P PV.
//
// The PV k-dim (keys, 64 = 2 frags of 32) is ORDER-INVARIANT, so we permute it:
//   slot(ks,quad,j) = key (ks + 2*(j>>2))*16 + quad*4 + (j&3)
// With this permutation the B-operand fragment for frag ks is exactly
// {s[ks][0..3], s[ks+2][0..3]} — lane-local, NO cross-lane traffic, no Ps LDS.
// The A-side (V^T) reads the same permutation: two bf16x4 loads (the two 4-key
// runs, 16ks+4q and +32) per former ds_read_b128. Vs staging is UNCHANGED
// (each swizzled 16B slot still holds a contiguous 8-key group; identity
// 8*(q>>1)+4*(q&1) = 4*q makes the runs line up); bank analysis of the b64
// reads: 2 lanes/bank = free (m136).
//
// + T13 defer-max: skip O-rescale when __all(mx <= m_s + 8) (P bounded by 2^8).
// + T5 s_setprio(1) around both MFMA clusters.
__global__ __launch_bounds__(256, 2)
void flash_attn(const bf16_t* __restrict__ qkv, const bf16_t* __restrict__ Kb,
                const bf16_t* __restrict__ Vt, bf16_t* __restrict__ Ob) {
  __shared__ __align__(16) bf16_t Ks[2][64 * 128];   // (key, d), swizzle grp^(row&15)
  __shared__ __align__(16) bf16_t Vs[2][128 * 64];   // (d, key), swizzle grp^(row&7)

  const int tid = threadIdx.x;
  const int wave = tid >> 6, lane = tid & 63;
  const int quad = lane >> 4, l16 = lane & 15;
  const int nQT = T_ / 64;  // 32
  const int bid = blockIdx.x;
  const int bh = bid % (B_ * NH_);
  const int qt = (nQT - 1) - (bid / (B_ * NH_));   // heavy-first
  const int h = bh % NH_;
  const int b = bh / NH_;
  const int kv = h >> 2;    // GQA: n_rep = 4

  const bf16_t* kbase = Kb + ((size_t)(b * NKV_ + kv) * T_) * HD_;
  const bf16_t* vbase = Vt + ((size_t)(b * NKV_ + kv) * HD_) * T_;

  auto stage = [&](int kt, int bufi) {
#pragma unroll
    for (int i = 0; i < 4; i++) {
      int e = i * 256 + tid;
      int row = e >> 4, grp = e & 15;
      int gg = grp ^ (row & 15);
      async_copy16(kbase + (size_t)(kt * 64 + row) * HD_ + gg * 8, &Ks[bufi][e * 8]);
    }
#pragma unroll
    for (int i = 0; i < 4; i++) {
      int e = i * 256 + tid;
      int row = e >> 3, grp = e & 7;
      int gg = grp ^ (row & 7);
      async_copy16(vbase + (size_t)row * T_ + kt * 64 + gg * 8, &Vs[bufi][e * 8]);
    }
  };

  stage(0, 0);  // prefetch first tile before anything else

  // Q fragments (B-operand): lane n=l16 -> q row t_row, holds d = ks*32+quad*8+j.
  bf16x8 qf[4];
  {
    const int t_row = qt * 64 + wave * 16 + l16;
    const bf16_t* qptr = qkv + (size_t)(b * T_ + t_row) * NQKV + h * HD_;
    bf16x8 qraw[4];
#pragma unroll
    for (int ks = 0; ks < 4; ks++)
      qraw[ks] = *(const bf16x8*)(qptr + ks * 32 + quad * 8);
    const float scale = 0.12751651541057752f;  // 1/sqrt(128)*log2(e)
#pragma unroll
    for (int ks = 0; ks < 2; ks++)
#pragma unroll
      for (int j = 0; j < 8; j++) {
        int d = ks * 32 + quad * 8 + j;        // < 64
        float ang = (float)t_row * __expf(-0.14391156816f * (float)d);
        float sn, cs;
        __sincosf(ang, &sn, &cs);
        float lo = (float)qraw[ks][j], hi = (float)qraw[ks + 2][j];
        qf[ks][j]     = (bf16_t)((lo * cs - hi * sn) * scale);
        qf[ks + 2][j] = (bf16_t)((hi * cs + lo * sn) * scale);
      }
  }

  // O^T accumulators: o[dt][r] = O^T[d = dt*16+quad*4+r][q = l16]
  floatx4 o[8];
#pragma unroll
  for (int i = 0; i < 8; i++) o[i] = floatx4{0.f, 0.f, 0.f, 0.f};
  float m_s = -1e30f, l_s = 0.f;  // per-lane: this lane's q-row state

  for (int kt = 0; kt <= qt; kt++) {
    const int bufi = kt & 1;
    // barrier: (a) drains vmcnt -> staging of THIS tile (issued last iter) done;
    // (b) all waves finished compute on the buffer we are about to overwrite.
    __syncthreads();
    if (kt < qt) stage(kt + 1, bufi ^ 1);  // prefetch next tile (other buffer)

    // S^T = K Q^T : s[nt][r] = S^T[key = nt*16+quad*4+r][q = l16]
    floatx4 s[4];
#pragma unroll
    for (int nt = 0; nt < 4; nt++) s[nt] = floatx4{0.f, 0.f, 0.f, 0.f};
    __builtin_amdgcn_s_setprio(1);
#pragma unroll
    for (int ks = 0; ks < 4; ks++) {
      int grp = ks * 4 + quad;
#pragma unroll
      for (int nt = 0; nt < 4; nt++) {
        int row = nt * 16 + l16;
        bf16x8 kf = *(const bf16x8*)(&Ks[bufi][row * 128 + ((grp ^ (row & 15)) << 3)]);
        s[nt] = __builtin_amdgcn_mfma_f32_16x16x32_bf16(kf, qf[ks], s[nt], 0, 0, 0);
      }
    }
    __builtin_amdgcn_s_setprio(0);

    // causal mask (only the diagonal tile needs it): key_local > q_local
    if (kt == qt) {
      int qlocal = wave * 16 + l16;
#pragma unroll
      for (int nt = 0; nt < 4; nt++)
#pragma unroll
        for (int r = 0; r < 4; r++) {
          int klocal = nt * 16 + quad * 4 + r;
          if (klocal > qlocal) s[nt][r] = -1e30f;
        }
    }

    // online softmax, exp2 domain; all 16 values in this lane share one q-row.
    float mx = fmaxf(fmaxf(s[0][0], s[0][1]), fmaxf(s[0][2], s[0][3]));
#pragma unroll
    for (int nt = 1; nt < 4; nt++)
      mx = fmaxf(mx, fmaxf(fmaxf(s[nt][0], s[nt][1]), fmaxf(s[nt][2], s[nt][3])));
    mx = fmaxf(mx, __shfl_xor(mx, 16, 64));
    mx = fmaxf(mx, __shfl_xor(mx, 32, 64));
    // T13 defer-max: only rescale when the running max grew by > 8 (exp2 dom);
    // otherwise keep m_s, P values bounded by 2^8 = 256 (fine in bf16/f32).
    if (!__all(mx <= m_s + 8.0f)) {
      float mnew = fmaxf(m_s, mx);
      float alpha = __builtin_amdgcn_exp2f(m_s - mnew);
      m_s = mnew;
      l_s *= alpha;
#pragma unroll
      for (int dt = 0; dt < 8; dt++) o[dt] *= alpha;
    }
    float sum = 0.f;
#pragma unroll
    for (int nt = 0; nt < 4; nt++)
#pragma unroll
      for (int r = 0; r < 4; r++) {
        float p = __builtin_amdgcn_exp2f(s[nt][r] - m_s);
        s[nt][r] = p;
        sum += p;
      }
    sum += __shfl_xor(sum, 16, 64);
    sum += __shfl_xor(sum, 32, 64);
    l_s += sum;

    // O^T += V^T P^T with register-resident P (key-permuted kdim, see header).
    __builtin_amdgcn_s_setprio(1);
#pragma unroll
    for (int ks = 0; ks < 2; ks++) {
      bf16x8 pf;
#pragma unroll
      for (int j = 0; j < 4; j++) {
        pf[j]     = (bf16_t)s[ks][j];
        pf[j + 4] = (bf16_t)s[ks + 2][j];
      }
      const int glo = 2 * ks + (quad >> 1);   // 16B-slot of keys [16ks+4q, +4)
      const int ghi = glo + 4;                // 16B-slot of keys [16ks+32+4q, +4)
      const int half = (quad & 1) * 4;        // 8B half within the 16B slot
#pragma unroll
      for (int dt = 0; dt < 8; dt++) {
        int row = dt * 16 + l16;
        int sw = row & 7;
        const bf16_t* vrow = &Vs[bufi][row * 64];
        bf16x4 vlo = *(const bf16x4*)(vrow + (((glo ^ sw) << 3) + half));
        bf16x4 vhi = *(const bf16x4*)(vrow + (((ghi ^ sw) << 3) + half));
        bf16x8 vf = __builtin_shufflevector(vlo, vhi, 0, 1, 2, 3, 4, 5, 6, 7);
        o[dt] = __builtin_amdgcn_mfma_f32_16x16x32_bf16(vf, pf, o[dt], 0, 0, 0);
      }
    }
    __builtin_amdgcn_s_setprio(0);
  }

  // epilogue: lane owns q-row qg = qt*64 + wave*16 + l16; d = dt*16+quad*4+r.
  {
    int qg = qt * 64 + wave * 16 + l16;
    float inv_l = 1.f / l_s;
    size_t base = ((size_t)(b * T_) + qg) * D_ + h * HD_;
#pragma unroll
    for (int dt = 0; dt < 8; dt++) {
      bf16x4 w;
#pragma unroll
      for (int r = 0; r < 4; r++) w[r] = (bf16_t)(o[dt][r] * inv_l);
      *(bf16x4*)(Ob + base + dt * 16 + quad * 4) = w;
    }
  }
}

// ---------------------------------------------------------------------------
extern "C" void kernel_launch(void* const* d_in, const int* in_sizes, int n_in,
                              void* d_out, int out_size, void* d_ws, size_t ws_size,
                              hipStream_t stream) {
  const float* x  = (const float*)d_in[0];
  const float* wq = (const float*)d_in[1];
  const float* wk = (const float*)d_in[2];
  const float* wv = (const float*)d_in[3];
  const float* wo = (const float*)d_in[4];
  float* out = (float*)d_out;

  // workspace layout (bf16 elems); attn output aliases x_bf (x_bf dead after GEMM1)
  bf16_t* x_bf   = (bf16_t*)d_ws;                          // 4096*2048
  bf16_t* attn_o = x_bf;                                   // alias
  bf16_t* wqkv_t = x_bf + (size_t)MROWS * D_;              // 3072*2048
  bf16_t* wo_t   = wqkv_t + (size_t)NQKV * D_;             // 2048*2048
  bf16_t* qkv    = wo_t + (size_t)D_ * D_;                 // 4096*3072
  bf16_t* Kb     = qkv + (size_t)MROWS * NQKV;             // 2*4*2048*128
  bf16_t* Vt     = Kb + (size_t)B_ * NKV_ * T_ * HD_;      // 2*4*128*2048

  // 1. fused prep: x cast + all 4 weight transposes in ONE dispatch
  prep_fused<<<dim3(64, 64, 5), dim3(32, 8), 0, stream>>>(
      wq, wk, wv, wo, x,
      wqkv_t, wqkv_t + (size_t)2048 * D_, wqkv_t + (size_t)2560 * D_, wo_t, x_bf);

  // 2. fused QKV projection: (4096,2048) x (2048,3072) -> bf16
  gemm_bt<bf16_t><<<(MROWS / 128) * (NQKV / 128), 256, 0, stream>>>(
      x_bf, wqkv_t, qkv, MROWS, NQKV, D_);

  // 3. fused K-RoPE + V transpose (Q-RoPE fused into flash)
  kv_prep<<<ROPE_BLOCKS + (T_ / 32) * (HD_ / 32) * B_ * NKV_, 256, 0, stream>>>(
      qkv, Kb, Vt);

  // 4. causal flash attention: v5, register-P + defer-max + setprio
  flash_attn<<<B_ * NH_ * (T_ / 64), 256, 0, stream>>>(qkv, Kb, Vt, attn_o);

  // 5. output projection: (4096,2048) x (2048,2048) -> fp32
  gemm_bt<float><<<(MROWS / 128) * (D_ / 128), 256, 0, stream>>>(
      attn_o, wo_t, out, MROWS, D_, D_);
}

// Round 3
// 271.510 us; speedup vs baseline: 1.0535x; 1.0535x over previous
//
#include <hip/hip_runtime.h>
#include <hip/hip_bf16.h>
#include <math.h>

// Problem constants
#define B_   2
#define T_   2048
#define D_   2048
#define NH_  16
#define NKV_ 4
#define HD_  128
#define MROWS (B_*T_)          // 4096
#define NQKV  (NH_*HD_ + 2*NKV_*HD_)  // 3072

typedef __bf16 bf16_t;
typedef __bf16 bf16x8 __attribute__((ext_vector_type(8)));
typedef __bf16 bf16x4 __attribute__((ext_vector_type(4)));
typedef float  floatx4 __attribute__((ext_vector_type(4)));

// ---------------------------------------------------------------------------
// async global->LDS. LDS dest must be wave-uniform base + lane*size.
__device__ __forceinline__ void async_copy16(const bf16_t* gsrc, bf16_t* ldst) {
  __builtin_amdgcn_global_load_lds(
      (const __attribute__((address_space(1))) unsigned int*)gsrc,
      (__attribute__((address_space(3))) unsigned int*)ldst, 16, 0, 0);
}
__device__ __forceinline__ void async_copy4(const bf16_t* gsrc, bf16_t* ldst) {
  __builtin_amdgcn_global_load_lds(
      (const __attribute__((address_space(1))) unsigned int*)gsrc,
      (__attribute__((address_space(3))) unsigned int*)ldst, 4, 0, 0);
}

// ---------------------------------------------------------------------------
// Fused prep: z=0..3 -> transpose+cast weight z; z=4 -> elementwise cast of x.
// grid (64, 64, 5), block (32,8)
__global__ void prep_fused(const float* __restrict__ s0, const float* __restrict__ s1,
                           const float* __restrict__ s2, const float* __restrict__ s3,
                           const float* __restrict__ sx,
                           bf16_t* __restrict__ d0, bf16_t* __restrict__ d1,
                           bf16_t* __restrict__ d2, bf16_t* __restrict__ d3,
                           bf16_t* __restrict__ dx) {
  const int z = blockIdx.z;
  const int tx = threadIdx.x, ty = threadIdx.y;
  if (z == 4) {
    int i = ((blockIdx.y * 64 + blockIdx.x) * 256 + ty * 32 + tx) * 8;
    float4 a = *(const float4*)(sx + i);
    float4 b = *(const float4*)(sx + i + 4);
    bf16x8 v;
    v[0]=(bf16_t)a.x; v[1]=(bf16_t)a.y; v[2]=(bf16_t)a.z; v[3]=(bf16_t)a.w;
    v[4]=(bf16_t)b.x; v[5]=(bf16_t)b.y; v[6]=(bf16_t)b.z; v[7]=(bf16_t)b.w;
    *(bf16x8*)(dx + i) = v;
    return;
  }
  const int N = (z == 1 || z == 2) ? 512 : 2048;
  const int n0 = blockIdx.x * 32;
  if (n0 >= N) return;
  const float* src = (z == 0) ? s0 : (z == 1) ? s1 : (z == 2) ? s2 : s3;
  bf16_t*      dst = (z == 0) ? d0 : (z == 1) ? d1 : (z == 2) ? d2 : d3;
  const int K = 2048;
  __shared__ float tile[32][33];
  int k0 = blockIdx.y * 32;
#pragma unroll
  for (int r = 0; r < 4; r++)
    tile[ty + r*8][tx] = src[(size_t)(k0 + ty + r*8) * N + n0 + tx];
  __syncthreads();
#pragma unroll
  for (int r = 0; r < 4; r++)
    dst[(size_t)(n0 + ty + r*8) * K + k0 + tx] = (bf16_t)tile[tx][ty + r*8];
}

// ---------------------------------------------------------------------------
// C(M,N) = A(M,K) * Bt(N,K)^T   all bf16 in, OUT_T out.
// 128x128 tile, BK=64, 4 waves (2x2 of 64x64), 16x16x32 MFMA.
template <typename OUT_T>
__global__ __launch_bounds__(256, 3)
void gemm_bt(const bf16_t* __restrict__ A, const bf16_t* __restrict__ Bt,
             OUT_T* __restrict__ C, int M, int N, int K) {
  __shared__ __align__(16) bf16_t As[128 * 64];
  __shared__ __align__(16) bf16_t Bs[128 * 64];
  const int tid  = threadIdx.x;
  const int wave = tid >> 6, lane = tid & 63;
  const int quad = lane >> 4, l16 = lane & 15;
  const int nBlocksM = M >> 7;
  const int bm = blockIdx.x % nBlocksM, bn = blockIdx.x / nBlocksM;
  const int m0 = bm * 128, n0 = bn * 128;
  const int wm = (wave >> 1) * 64, wn = (wave & 1) * 64;

  floatx4 acc[4][4];
#pragma unroll
  for (int i = 0; i < 4; i++)
#pragma unroll
    for (int j = 0; j < 4; j++) acc[i][j] = floatx4{0.f, 0.f, 0.f, 0.f};

  for (int k0 = 0; k0 < K; k0 += 64) {
    __syncthreads();
#pragma unroll
    for (int i = 0; i < 4; i++) {
      int e = i * 256 + tid;
      int row = e >> 3, grp = e & 7;
      int gg = grp ^ (row & 7);
      async_copy16(A + (size_t)(m0 + row) * K + k0 + gg * 8, As + e * 8);
    }
#pragma unroll
    for (int i = 0; i < 4; i++) {
      int e = i * 256 + tid;
      int row = e >> 3, grp = e & 7;
      int gg = grp ^ (row & 7);
      async_copy16(Bt + (size_t)(n0 + row) * K + k0 + gg * 8, Bs + e * 8);
    }
    __syncthreads();
#pragma unroll
    for (int ks = 0; ks < 2; ks++) {
      bf16x8 af[4], bfr[4];
      int grp = ks * 4 + quad;
#pragma unroll
      for (int mi = 0; mi < 4; mi++) {
        int row = wm + mi * 16 + l16;
        af[mi] = *(const bf16x8*)(As + row * 64 + ((grp ^ (row & 7)) << 3));
      }
#pragma unroll
      for (int ni = 0; ni < 4; ni++) {
        int row = wn + ni * 16 + l16;
        bfr[ni] = *(const bf16x8*)(Bs + row * 64 + ((grp ^ (row & 7)) << 3));
      }
#pragma unroll
      for (int mi = 0; mi < 4; mi++)
#pragma unroll
        for (int ni = 0; ni < 4; ni++)
          acc[mi][ni] = __builtin_amdgcn_mfma_f32_16x16x32_bf16(af[mi], bfr[ni], acc[mi][ni], 0, 0, 0);
    }
  }
#pragma unroll
  for (int mi = 0; mi < 4; mi++) {
#pragma unroll
    for (int r = 0; r < 4; r++) {
      int row = m0 + wm + mi * 16 + quad * 4 + r;
      size_t base = (size_t)row * N + n0 + wn;
#pragma unroll
      for (int ni = 0; ni < 4; ni++)
        C[base + ni * 16 + l16] = (OUT_T)acc[mi][ni][r];
    }
  }
}

// ---------------------------------------------------------------------------
// Fused K-RoPE + V-transpose (one dispatch; branch is block-uniform).
#define ROPE_BLOCKS ((MROWS * NKV_ * 64) / 256)   // 4096
__global__ void kv_prep(const bf16_t* __restrict__ qkv, bf16_t* __restrict__ Kb,
                        bf16_t* __restrict__ Vt) {
  if (blockIdx.x < ROPE_BLOCKS) {
    int g = blockIdx.x * 256 + threadIdx.x;
    int j = g & 63;
    int rest = g >> 6;
    int kvh = rest & 3;
    int row = rest >> 2;                // b*T + t
    int t = row & (T_ - 1);
    int b = row >> 11;                  // T_ = 2048
    const bf16_t* src = qkv + (size_t)row * NQKV + NH_ * HD_ + kvh * HD_;
    float ang = (float)t * __expf(-0.14391156816f * (float)j);
    float sn, cs;
    __sincosf(ang, &sn, &cs);
    float x0 = (float)src[j];
    float x1 = (float)src[j + 64];
    bf16_t* dst = Kb + ((size_t)(b * NKV_ + kvh) * T_ + t) * HD_;
    dst[j]      = (bf16_t)(x0 * cs - x1 * sn);
    dst[j + 64] = (bf16_t)(x1 * cs + x0 * sn);
    return;
  }
  __shared__ float tile[32][33];
  int bb = blockIdx.x - ROPE_BLOCKS;          // [0, 2048)
  int bx = bb & 63, by = (bb >> 6) & 3, bz = bb >> 8;
  int t0 = bx * 32, d0 = by * 32;
  int b = bz / NKV_, kvh = bz % NKV_;
  int tx = threadIdx.x & 31, ty = threadIdx.x >> 5;
#pragma unroll
  for (int r = 0; r < 4; r++) {
    int t = t0 + ty + r * 8;
    tile[ty + r*8][tx] =
        (float)qkv[(size_t)(b * T_ + t) * NQKV + (NH_ + NKV_) * HD_ + kvh * HD_ + d0 + tx];
  }
  __syncthreads();
#pragma unroll
  for (int r = 0; r < 4; r++) {
    int d = d0 + ty + r * 8;
    Vt[((size_t)(b * NKV_ + kvh) * HD_ + d) * T_ + t0 + tx] = (bf16_t)tile[tx][ty + r*8];
  }
}

// ---------------------------------------------------------------------------
// Flash attention v6: register-P PV with INTERLEAVED V LDS layout.
//
// Register-P (v5, verified): PV k-dim permuted so the B-fragment for frag ks
// is {s[ks][0..3], s[ks+2][0..3]} — lane-local, no P LDS round-trip.
// v5's flaw (measured: bank conflicts 1.6M->8.65M): the A-side needed two 8B
// reads hitting even banks only (4-way conflict). v6 fix: store V INTERLEAVED
// so each 16B granule G = ks*4+q holds keys [16ks+4q+0..3 | 16ks+32+4q+0..3],
// swizzled at slot G^(row&7). The PV read is then ONE ds_read_b128 at the
// byte-identical address pattern the v4 baseline measured at 1.6M conflicts.
// Staging uses 16x size-4 global_load_lds (sizes 4/12/16 per m03) with a
// pre-permuted per-lane GLOBAL source (m173 pattern) and linear LDS dest:
//   rr = i*8 + (tid>>5);  rr&7 == (tid>>5)&7  (i-invariant!)
//   G  = ((tid>>2)&7) ^ (rr&7);  k = 16*(G>>2) + 32*((tid>>1)&1) + 4*(G&3) + 2*(tid&1)
//   src = vbase + rr*T + kt*64 + k (4B = 2 keys);  dest elem = i*512 + tid*2
// Each wave-instr writes 256B contiguous LDS (conflict-free DMA) and reads two
// full 128B global rows (coalesced). Bijection (i,tid)->(rr,k) verified.
//
// + T13 defer-max + T5 s_setprio (unchanged from v5).
__global__ __launch_bounds__(256, 2)
void flash_attn(const bf16_t* __restrict__ qkv, const bf16_t* __restrict__ Kb,
                const bf16_t* __restrict__ Vt, bf16_t* __restrict__ Ob) {
  __shared__ __align__(16) bf16_t Ks[2][64 * 128];   // (key, d), swizzle grp^(row&15)
  __shared__ __align__(16) bf16_t Vs[2][128 * 64];   // (d, key-interleaved), see header

  const int tid = threadIdx.x;
  const int wave = tid >> 6, lane = tid & 63;
  const int quad = lane >> 4, l16 = lane & 15;
  const int nQT = T_ / 64;  // 32
  const int bid = blockIdx.x;
  const int bh = bid % (B_ * NH_);
  const int qt = (nQT - 1) - (bid / (B_ * NH_));   // heavy-first
  const int h = bh % NH_;
  const int b = bh / NH_;
  const int kv = h >> 2;    // GQA: n_rep = 4

  const bf16_t* kbase = Kb + ((size_t)(b * NKV_ + kv) * T_) * HD_;
  const bf16_t* vbase = Vt + ((size_t)(b * NKV_ + kv) * HD_) * T_;

  // per-thread V staging source permutation (i-invariant, see header)
  const int rrb = tid >> 5;                       // rr & 7 for all i
  const int G0  = ((tid >> 2) & 7) ^ rrb;
  const int kk  = ((G0 >> 2) << 4) + (((tid >> 1) & 1) << 5)
                + ((G0 & 3) << 2) + ((tid & 1) << 1);
  const bf16_t* vsrc0 = vbase + (size_t)rrb * T_ + kk;

  auto stage = [&](int kt, int bufi) {
#pragma unroll
    for (int i = 0; i < 4; i++) {
      int e = i * 256 + tid;
      int row = e >> 4, grp = e & 15;
      int gg = grp ^ (row & 15);
      async_copy16(kbase + (size_t)(kt * 64 + row) * HD_ + gg * 8, &Ks[bufi][e * 8]);
    }
    const bf16_t* vs = vsrc0 + kt * 64;
    bf16_t* vd = &Vs[bufi][tid * 2];
#pragma unroll
    for (int i = 0; i < 16; i++)
      async_copy4(vs + (size_t)i * 8 * T_, vd + i * 512);
  };

  stage(0, 0);  // prefetch first tile before anything else

  // Q fragments (B-operand): lane n=l16 -> q row t_row, holds d = ks*32+quad*8+j.
  bf16x8 qf[4];
  {
    const int t_row = qt * 64 + wave * 16 + l16;
    const bf16_t* qptr = qkv + (size_t)(b * T_ + t_row) * NQKV + h * HD_;
    bf16x8 qraw[4];
#pragma unroll
    for (int ks = 0; ks < 4; ks++)
      qraw[ks] = *(const bf16x8*)(qptr + ks * 32 + quad * 8);
    const float scale = 0.12751651541057752f;  // 1/sqrt(128)*log2(e)
#pragma unroll
    for (int ks = 0; ks < 2; ks++)
#pragma unroll
      for (int j = 0; j < 8; j++) {
        int d = ks * 32 + quad * 8 + j;        // < 64
        float ang = (float)t_row * __expf(-0.14391156816f * (float)d);
        float sn, cs;
        __sincosf(ang, &sn, &cs);
        float lo = (float)qraw[ks][j], hi = (float)qraw[ks + 2][j];
        qf[ks][j]     = (bf16_t)((lo * cs - hi * sn) * scale);
        qf[ks + 2][j] = (bf16_t)((hi * cs + lo * sn) * scale);
      }
  }

  // O^T accumulators: o[dt][r] = O^T[d = dt*16+quad*4+r][q = l16]
  floatx4 o[8];
#pragma unroll
  for (int i = 0; i < 8; i++) o[i] = floatx4{0.f, 0.f, 0.f, 0.f};
  float m_s = -1e30f, l_s = 0.f;  // per-lane: this lane's q-row state

  for (int kt = 0; kt <= qt; kt++) {
    const int bufi = kt & 1;
    // barrier: (a) drains vmcnt -> staging of THIS tile (issued last iter) done;
    // (b) all waves finished compute on the buffer we are about to overwrite.
    __syncthreads();
    if (kt < qt) stage(kt + 1, bufi ^ 1);  // prefetch next tile (other buffer)

    // S^T = K Q^T : s[nt][r] = S^T[key = nt*16+quad*4+r][q = l16]
    floatx4 s[4];
#pragma unroll
    for (int nt = 0; nt < 4; nt++) s[nt] = floatx4{0.f, 0.f, 0.f, 0.f};
    __builtin_amdgcn_s_setprio(1);
#pragma unroll
    for (int ks = 0; ks < 4; ks++) {
      int grp = ks * 4 + quad;
#pragma unroll
      for (int nt = 0; nt < 4; nt++) {
        int row = nt * 16 + l16;
        bf16x8 kf = *(const bf16x8*)(&Ks[bufi][row * 128 + ((grp ^ (row & 15)) << 3)]);
        s[nt] = __builtin_amdgcn_mfma_f32_16x16x32_bf16(kf, qf[ks], s[nt], 0, 0, 0);
      }
    }
    __builtin_amdgcn_s_setprio(0);

    // causal mask (only the diagonal tile needs it): key_local > q_local
    if (kt == qt) {
      int qlocal = wave * 16 + l16;
#pragma unroll
      for (int nt = 0; nt < 4; nt++)
#pragma unroll
        for (int r = 0; r < 4; r++) {
          int klocal = nt * 16 + quad * 4 + r;
          if (klocal > qlocal) s[nt][r] = -1e30f;
        }
    }

    // online softmax, exp2 domain; all 16 values in this lane share one q-row.
    float mx = fmaxf(fmaxf(s[0][0], s[0][1]), fmaxf(s[0][2], s[0][3]));
#pragma unroll
    for (int nt = 1; nt < 4; nt++)
      mx = fmaxf(mx, fmaxf(fmaxf(s[nt][0], s[nt][1]), fmaxf(s[nt][2], s[nt][3])));
    mx = fmaxf(mx, __shfl_xor(mx, 16, 64));
    mx = fmaxf(mx, __shfl_xor(mx, 32, 64));
    // T13 defer-max: only rescale when the running max grew by > 8 (exp2 dom).
    if (!__all(mx <= m_s + 8.0f)) {
      float mnew = fmaxf(m_s, mx);
      float alpha = __builtin_amdgcn_exp2f(m_s - mnew);
      m_s = mnew;
      l_s *= alpha;
#pragma unroll
      for (int dt = 0; dt < 8; dt++) o[dt] *= alpha;
    }
    float sum = 0.f;
#pragma unroll
    for (int nt = 0; nt < 4; nt++)
#pragma unroll
      for (int r = 0; r < 4; r++) {
        float p = __builtin_amdgcn_exp2f(s[nt][r] - m_s);
        s[nt][r] = p;
        sum += p;
      }
    sum += __shfl_xor(sum, 16, 64);
    sum += __shfl_xor(sum, 32, 64);
    l_s += sum;

    // O^T += V^T P^T, register-resident P, single b128 V read per MFMA.
    __builtin_amdgcn_s_setprio(1);
#pragma unroll
    for (int ks = 0; ks < 2; ks++) {
      bf16x8 pf;
#pragma unroll
      for (int j = 0; j < 4; j++) {
        pf[j]     = (bf16_t)s[ks][j];
        pf[j + 4] = (bf16_t)s[ks + 2][j];
      }
      const int G = ks * 4 + quad;   // interleaved granule: matches pf key order
#pragma unroll
      for (int dt = 0; dt < 8; dt++) {
        int row = dt * 16 + l16;
        bf16x8 vf = *(const bf16x8*)(&Vs[bufi][row * 64 + ((G ^ (row & 7)) << 3)]);
        o[dt] = __builtin_amdgcn_mfma_f32_16x16x32_bf16(vf, pf, o[dt], 0, 0, 0);
      }
    }
    __builtin_amdgcn_s_setprio(0);
  }

  // epilogue: lane owns q-row qg = qt*64 + wave*16 + l16; d = dt*16+quad*4+r.
  {
    int qg = qt * 64 + wave * 16 + l16;
    float inv_l = 1.f / l_s;
    size_t base = ((size_t)(b * T_) + qg) * D_ + h * HD_;
#pragma unroll
    for (int dt = 0; dt < 8; dt++) {
      bf16x4 w;
#pragma unroll
      for (int r = 0; r < 4; r++) w[r] = (bf16_t)(o[dt][r] * inv_l);
      *(bf16x4*)(Ob + base + dt * 16 + quad * 4) = w;
    }
  }
}

// ---------------------------------------------------------------------------
extern "C" void kernel_launch(void* const* d_in, const int* in_sizes, int n_in,
                              void* d_out, int out_size, void* d_ws, size_t ws_size,
                              hipStream_t stream) {
  const float* x  = (const float*)d_in[0];
  const float* wq = (const float*)d_in[1];
  const float* wk = (const float*)d_in[2];
  const float* wv = (const float*)d_in[3];
  const float* wo = (const float*)d_in[4];
  float* out = (float*)d_out;

  // workspace layout (bf16 elems); attn output aliases x_bf (x_bf dead after GEMM1)
  bf16_t* x_bf   = (bf16_t*)d_ws;                          // 4096*2048
  bf16_t* attn_o = x_bf;                                   // alias
  bf16_t* wqkv_t = x_bf + (size_t)MROWS * D_;              // 3072*2048
  bf16_t* wo_t   = wqkv_t + (size_t)NQKV * D_;             // 2048*2048
  bf16_t* qkv    = wo_t + (size_t)D_ * D_;                 // 4096*3072
  bf16_t* Kb     = qkv + (size_t)MROWS * NQKV;             // 2*4*2048*128
  bf16_t* Vt     = Kb + (size_t)B_ * NKV_ * T_ * HD_;      // 2*4*128*2048

  // 1. fused prep: x cast + all 4 weight transposes in ONE dispatch
  prep_fused<<<dim3(64, 64, 5), dim3(32, 8), 0, stream>>>(
      wq, wk, wv, wo, x,
      wqkv_t, wqkv_t + (size_t)2048 * D_, wqkv_t + (size_t)2560 * D_, wo_t, x_bf);

  // 2. fused QKV projection: (4096,2048) x (2048,3072) -> bf16
  gemm_bt<bf16_t><<<(MROWS / 128) * (NQKV / 128), 256, 0, stream>>>(
      x_bf, wqkv_t, qkv, MROWS, NQKV, D_);

  // 3. fused K-RoPE + V transpose (Q-RoPE fused into flash)
  kv_prep<<<ROPE_BLOCKS + (T_ / 32) * (HD_ / 32) * B_ * NKV_, 256, 0, stream>>>(
      qkv, Kb, Vt);

  // 4. causal flash attention: v6, interleaved-V register-P
  flash_attn<<<B_ * NH_ * (T_ / 64), 256, 0, stream>>>(qkv, Kb, Vt, attn_o);

  // 5. output projection: (4096,2048) x (2048,2048) -> fp32
  gemm_bt<float><<<(MROWS / 128) * (D_ / 128), 256, 0, stream>>>(
      attn_o, wo_t, out, MROWS, D_, D_);
}